// Round 2
// baseline (5025.671 us; speedup 1.0000x reference)
//
#include <hip/hip_runtime.h>

// =====================================================================
// DecoderLayer: selfMHA -> LN -> crossMHA -> LN -> 32xLSTM(pipelined)
//               -> pointwise conv -> LN
// Round 2: LSTM restructured: thread-per-(batch,unit), weights+c in regs,
//          one barrier/step, 512 blocks (2/CU). Rest unchanged.
// =====================================================================

#define EPS_LN 1e-5f

// ---------------- fp32 tiled GEMM: C[M,512] = A[M,512]@B[512,512]+bias ----
__global__ __launch_bounds__(256)
void gemm512(const float* __restrict__ A, const float* __restrict__ B,
             const float* __restrict__ bias, float* __restrict__ C, int M) {
  __shared__ float As[16][68];
  __shared__ float Bs[16][68];
  const int t  = threadIdx.x;
  const int tx = t & 15, ty = t >> 4;
  const int row0 = blockIdx.y * 64;
  const int col0 = blockIdx.x * 64;
  float acc[4][4] = {};
  for (int k0 = 0; k0 < 512; k0 += 16) {
#pragma unroll
    for (int i = 0; i < 4; i++) {
      int idx = t + i * 256;
      int m  = idx >> 4, kk = idx & 15;
      As[kk][m] = A[(row0 + m) * 512 + k0 + kk];
      int kb = idx >> 6, n = idx & 63;
      Bs[kb][n] = B[(k0 + kb) * 512 + col0 + n];
    }
    __syncthreads();
#pragma unroll
    for (int kk = 0; kk < 16; kk++) {
      float4 a4 = *(const float4*)&As[kk][ty * 4];
      float4 b4 = *(const float4*)&Bs[kk][tx * 4];
      float av[4] = {a4.x, a4.y, a4.z, a4.w};
      float bv[4] = {b4.x, b4.y, b4.z, b4.w};
#pragma unroll
      for (int i = 0; i < 4; i++)
#pragma unroll
        for (int j = 0; j < 4; j++) acc[i][j] += av[i] * bv[j];
    }
    __syncthreads();
  }
  float4 bias4 = *(const float4*)&bias[col0 + tx * 4];
#pragma unroll
  for (int i = 0; i < 4; i++) {
    int gr = row0 + ty * 4 + i;
    if (gr < M) {
      float4 o = make_float4(acc[i][0] + bias4.x, acc[i][1] + bias4.y,
                             acc[i][2] + bias4.z, acc[i][3] + bias4.w);
      *(float4*)&C[gr * 512 + col0 + tx * 4] = o;
    }
  }
}

// ---------------- attention: scores then softmax+PV, per (b,h) -----------
template <int S>
__global__ __launch_bounds__(256)
void attn_scores(const float* __restrict__ Q, const float* __restrict__ K,
                 float* __restrict__ P) {
  __shared__ float Qs[25][64];
  __shared__ float Ks[S][65];
  const int h = blockIdx.x, b = blockIdx.y, t = threadIdx.x;
  for (int idx = t; idx < 25 * 64; idx += 256) {
    int l = idx >> 6, e = idx & 63;
    Qs[l][e] = Q[(b * 25 + l) * 512 + h * 64 + e];
  }
  for (int idx = t; idx < S * 64; idx += 256) {
    int s = idx >> 6, e = idx & 63;
    Ks[s][e] = K[(b * S + s) * 512 + h * 64 + e];
  }
  __syncthreads();
  float* Pb = P + (size_t)(b * 8 + h) * 25 * S;
  for (int idx = t; idx < 25 * S; idx += 256) {
    int l = idx / S, s = idx % S;
    float acc = 0.f;
#pragma unroll
    for (int e = 0; e < 64; e++) acc += Qs[l][e] * Ks[s][e];
    Pb[idx] = acc * 0.125f;
  }
}

template <int S>
__global__ __launch_bounds__(256)
void attn_out(const float* __restrict__ P, const float* __restrict__ V,
              float* __restrict__ O) {
  __shared__ float Ps[25][S];
  __shared__ float Vs[S][64];
  const int h = blockIdx.x, b = blockIdx.y, t = threadIdx.x;
  const float* Pb = P + (size_t)(b * 8 + h) * 25 * S;
  for (int idx = t; idx < 25 * S; idx += 256) Ps[idx / S][idx % S] = Pb[idx];
  for (int idx = t; idx < S * 64; idx += 256) {
    int s = idx >> 6, e = idx & 63;
    Vs[s][e] = V[(b * S + s) * 512 + h * 64 + e];
  }
  __syncthreads();
  if (t < 25) {
    float mx = -1e30f;
    for (int s = 0; s < S; s++) mx = fmaxf(mx, Ps[t][s]);
    float sum = 0.f;
    for (int s = 0; s < S; s++) { float p = __expf(Ps[t][s] - mx); Ps[t][s] = p; sum += p; }
    float r = 1.f / sum;
    for (int s = 0; s < S; s++) Ps[t][s] *= r;
  }
  __syncthreads();
  for (int idx = t; idx < 25 * 64; idx += 256) {
    int l = idx >> 6, e = idx & 63;
    float acc = 0.f;
    for (int s = 0; s < S; s++) acc += Ps[l][s] * Vs[s][e];
    O[(b * 25 + l) * 512 + h * 64 + e] = acc;
  }
}

// ---------------- fused residual-add + LayerNorm (rows of 512) -----------
__global__ __launch_bounds__(128)
void add_ln(const float* __restrict__ a, const float* __restrict__ b,
            const float* __restrict__ gw, const float* __restrict__ bw,
            float* __restrict__ out) {
  const int row = blockIdx.x, t = threadIdx.x;
  float4 va = ((const float4*)(a + (size_t)row * 512))[t];
  float4 vb = ((const float4*)(b + (size_t)row * 512))[t];
  float4 v = make_float4(va.x + vb.x, va.y + vb.y, va.z + vb.z, va.w + vb.w);
  float s = v.x + v.y + v.z + v.w;
  float q = v.x * v.x + v.y * v.y + v.z * v.z + v.w * v.w;
#pragma unroll
  for (int off = 32; off > 0; off >>= 1) {
    s += __shfl_down(s, off);
    q += __shfl_down(q, off);
  }
  __shared__ float red[4];
  if ((t & 63) == 0) { red[(t >> 6) * 2] = s; red[(t >> 6) * 2 + 1] = q; }
  __syncthreads();
  float S_ = red[0] + red[2], Q_ = red[1] + red[3];
  float mean = S_ * (1.f / 512.f);
  float var  = Q_ * (1.f / 512.f) - mean * mean;
  float inv  = rsqrtf(var + EPS_LN);
  float4 g4 = ((const float4*)gw)[t];
  float4 b4 = ((const float4*)bw)[t];
  float4 o;
  o.x = (v.x - mean) * inv * g4.x + b4.x;
  o.y = (v.y - mean) * inv * g4.y + b4.y;
  o.z = (v.z - mean) * inv * g4.z + b4.z;
  o.w = (v.w - mean) * inv * g4.w + b4.w;
  ((float4*)(out + (size_t)row * 512))[t] = o;
}

// ---------------- transposes --------------------------------------------
__global__ void transpose_ld(const float* __restrict__ in, float* __restrict__ outp) {
  const int b = blockIdx.x, t = threadIdx.x;
  for (int idx = t; idx < 512 * 25; idx += 256) {
    int d = idx / 25, l2 = idx % 25;
    outp[((size_t)b * 512 + d) * 25 + l2] = in[((size_t)b * 25 + l2) * 512 + d];
  }
}
__global__ void transpose_dl(const float* __restrict__ in, float* __restrict__ outp) {
  const int b = blockIdx.x, t = threadIdx.x;
  for (int idx = t; idx < 25 * 512; idx += 256) {
    int l2 = idx / 512, c = idx % 512;
    outp[((size_t)b * 25 + l2) * 512 + c] = in[((size_t)b * 512 + c) * 25 + l2];
  }
}
__global__ void transpose_sq(const float* __restrict__ in, float* __restrict__ outp) {
  const int c = blockIdx.x, t = threadIdx.x;
  for (int o = t; o < 512; o += 256) outp[(size_t)c * 512 + o] = in[(size_t)o * 512 + c];
}

// ---------------- pipelined 32-layer LSTM --------------------------------
// Thread = (batch bi, unit u): all 4 gate rows of Wih/Whh in registers
// (200 VGPR), c-state in a register, h double-buffered in LDS -> ONE
// barrier per timestep, no gates[] LDS array.
// grid = 32 layers x 16 batch-groups (8 batches each) = 512 blocks = 2/CU.
// Co-residency: 8 waves/CU, VGPR<=256 (launch_bounds(256,2)), LDS ~6KB. ✓
#define NLAY 32
#define NT   512
#define NB   128
#define NGRP 16
#define BGRP 8           // batches per group
#define CHT  4           // timesteps per chunk
#define NCHK 128         // chunks (512/4)
#define RT   64          // ring depth in timesteps
#define RCHK (RT / CHT)  // ring depth in chunks = 16

__device__ __forceinline__ int ld_acq(int* p) {
  return __hip_atomic_load(p, __ATOMIC_ACQUIRE, __HIP_MEMORY_SCOPE_AGENT);
}
__device__ __forceinline__ void st_rel(int* p, int v) {
  __hip_atomic_store(p, v, __ATOMIC_RELEASE, __HIP_MEMORY_SCOPE_AGENT);
}
__device__ __forceinline__ float tanh_fast(float x) {
  // 1 - 2/(1+exp(2x)); saturates correctly for |x| large
  return 1.f - 2.f / (1.f + __expf(2.f * x));
}

__global__ __launch_bounds__(256, 2)
void lstm_pipeline(const float* __restrict__ y0, float* __restrict__ yout,
                   float* __restrict__ ring, int* __restrict__ prod,
                   int* __restrict__ cons,
                   const float* __restrict__ Wih, const float* __restrict__ Whh,
                   const float* __restrict__ bih, const float* __restrict__ bhh) {
  const int l = blockIdx.x / NGRP;
  const int g = blockIdx.x % NGRP;
  const int t = threadIdx.x;
  const int u  = t & 31;           // unit 0..24 active
  const int bi = t >> 5;           // batch-in-group 0..7
  const bool active = (u < 25);

  __shared__ float xbuf[CHT][BGRP][28];   // step inputs, k padded to 28
  __shared__ float hbuf[2][BGRP][28];     // double-buffered h

  // ---- per-thread register weights: rows {u,25+u,50+u,75+u} of Wih/Whh ----
  float wih[4][25], whh[4][25];
  float bias_r[4];
  float c_reg = 0.f;
  if (active) {
#pragma unroll
    for (int j = 0; j < 4; j++) {
      const float* wi = &Wih[((size_t)l * 100 + j * 25 + u) * 25];
      const float* wh = &Whh[((size_t)l * 100 + j * 25 + u) * 25];
#pragma unroll
      for (int k = 0; k < 25; k++) { wih[j][k] = wi[k]; whh[j][k] = wh[k]; }
      bias_r[j] = bih[l * 100 + j * 25 + u] + bhh[l * 100 + j * 25 + u];
    }
  }
  // zero initial h buffer (global step 0 reads hbuf[0])
  for (int idx = t; idx < 2 * BGRP * 28; idx += 256) (&hbuf[0][0][0])[idx] = 0.f;
  __syncthreads();

  for (int n = 0; n < NCHK; n++) {
    if (t == 0) {
      if (l > 0) {                        // wait for input chunk n
        int* p = &prod[(l - 1) * NGRP + g];
        while (ld_acq(p) < n + 1) __builtin_amdgcn_s_sleep(2);
      }
      if (l < NLAY - 1 && n >= RCHK) {    // wait for ring slots to free
        int* p = &cons[(l + 1) * NGRP + g];
        while (ld_acq(p) < n - RCHK + 1) __builtin_amdgcn_s_sleep(2);
      }
    }
    __syncthreads();
    // stage chunk input into LDS (4 steps x 8 batches x 25)
    for (int idx = t; idx < CHT * BGRP * 25; idx += 256) {
      int tc = idx / (BGRP * 25);
      int r  = idx % (BGRP * 25);
      int b2 = r / 25, k = r % 25;
      int tg = n * CHT + tc;
      int b  = g * BGRP + b2;
      float v = (l == 0)
          ? y0[((size_t)b * NT + tg) * 25 + k]
          : ring[(((size_t)(l - 1) * NB + b) * RT + (tg & (RT - 1))) * 25 + k];
      xbuf[tc][b2][k] = v;
    }
    __syncthreads();
    if (t == 0 && l > 0) st_rel(&cons[l * NGRP + g], n + 1);

#pragma unroll
    for (int tc = 0; tc < CHT; tc++) {
      const int tg = n * CHT + tc;
      const int p  = tg & 1;
      if (active) {
        float a0 = bias_r[0], a1 = bias_r[1], a2 = bias_r[2], a3 = bias_r[3];
        const float4* xp = (const float4*)&xbuf[tc][bi][0];
        const float4* hp = (const float4*)&hbuf[p][bi][0];
#pragma unroll
        for (int kk = 0; kk < 7; kk++) {
          float4 xv = xp[kk];
#pragma unroll
          for (int c4 = 0; c4 < 4; c4++) {
            int k = kk * 4 + c4;
            if (k < 25) {
              float xs = (&xv.x)[c4];
              a0 += wih[0][k] * xs; a1 += wih[1][k] * xs;
              a2 += wih[2][k] * xs; a3 += wih[3][k] * xs;
            }
          }
        }
#pragma unroll
        for (int kk = 0; kk < 7; kk++) {
          float4 hv = hp[kk];
#pragma unroll
          for (int c4 = 0; c4 < 4; c4++) {
            int k = kk * 4 + c4;
            if (k < 25) {
              float hs = (&hv.x)[c4];
              a0 += whh[0][k] * hs; a1 += whh[1][k] * hs;
              a2 += whh[2][k] * hs; a3 += whh[3][k] * hs;
            }
          }
        }
        float si = 1.f / (1.f + __expf(-a0));
        float sf = 1.f / (1.f + __expf(-a1));
        float so = 1.f / (1.f + __expf(-a3));
        c_reg = sf * c_reg + si * tanh_fast(a2);
        float h = so * tanh_fast(c_reg);
        hbuf[p ^ 1][bi][u] = h;
        int b = g * BGRP + bi;
        if (l == NLAY - 1)
          yout[((size_t)b * NT + tg) * 25 + u] = h;
        else
          ring[(((size_t)l * NB + b) * RT + (tg & (RT - 1))) * 25 + u] = h;
      }
      __syncthreads();
    }
    if (t == 0 && l < NLAY - 1) st_rel(&prod[l * NGRP + g], n + 1);
  }
}

// =====================================================================
extern "C" void kernel_launch(void* const* d_in, const int* in_sizes, int n_in,
                              void* d_out, int out_size, void* d_ws, size_t ws_size,
                              hipStream_t stream) {
  const float* x     = (const float*)d_in[0];
  const float* cross = (const float*)d_in[1];
  const float* Wq_s = (const float*)d_in[2];  const float* bq_s = (const float*)d_in[3];
  const float* Wk_s = (const float*)d_in[4];  const float* bk_s = (const float*)d_in[5];
  const float* Wv_s = (const float*)d_in[6];  const float* bv_s = (const float*)d_in[7];
  const float* Wo_s = (const float*)d_in[8];  const float* bo_s = (const float*)d_in[9];
  const float* Wq_c = (const float*)d_in[10]; const float* bq_c = (const float*)d_in[11];
  const float* Wk_c = (const float*)d_in[12]; const float* bk_c = (const float*)d_in[13];
  const float* Wv_c = (const float*)d_in[14]; const float* bv_c = (const float*)d_in[15];
  const float* Wo_c = (const float*)d_in[16]; const float* bo_c = (const float*)d_in[17];
  const float* g1 = (const float*)d_in[18]; const float* b1 = (const float*)d_in[19];
  const float* g2 = (const float*)d_in[20]; const float* b2 = (const float*)d_in[21];
  const float* g3 = (const float*)d_in[22]; const float* b3 = (const float*)d_in[23];
  const float* Wih = (const float*)d_in[24];
  const float* Whh = (const float*)d_in[25];
  const float* bih = (const float*)d_in[26];
  const float* bhh = (const float*)d_in[27];
  const float* Wc  = (const float*)d_in[28]; const float* bc = (const float*)d_in[29];
  float* out = (float*)d_out;
  float* ws  = (float*)d_ws;

  // ---- workspace layout (floats), liveness-based reuse ----
  constexpr size_t A = 1638400;    // 3200*512
  constexpr size_t Cc = 6291456;   // 12288*512
  float* x1    = ws;
  float* Qc    = ws + A;
  float* Kc    = ws + 2 * A;
  float* Vc    = ws + 2 * A + Cc;
  float* attnc = ws + 2 * A + 2 * Cc;
  float* Pc    = attnc + A;
  int*   ctr   = (int*)(Pc + 2457600);          // 1024 ints (prod|cons)
  // self-attention phase aliases
  float* Qs    = ws + 2 * A;
  float* Ks    = ws + 3 * A;
  float* Vs    = ws + 4 * A;
  float* attns = ws + 5 * A;
  float* tmp   = ws + 6 * A;
  float* Ps    = ws + 7 * A;
  // post-cross aliases
  float* tmp2  = ws + 2 * A;
  float* x2    = ws + 3 * A;
  float* y0b   = ws + 4 * A;
  float* youtb = ws + 5 * A;
  float* ringb = ws + 6 * A;       // 31*128*64*25 = 6,348,800 floats
  float* ytb   = ws + 2 * A;
  float* WcT   = ws + 6 * A;
  float* fy    = ws + 7 * A;

  hipMemsetAsync(ctr, 0, 1024 * sizeof(int), stream);

  dim3 blk(256);
  // ---- self attention ----
  gemm512<<<dim3(8, 50), blk, 0, stream>>>(x, Wq_s, bq_s, Qs, 3200);
  gemm512<<<dim3(8, 50), blk, 0, stream>>>(x, Wk_s, bk_s, Ks, 3200);
  gemm512<<<dim3(8, 50), blk, 0, stream>>>(x, Wv_s, bv_s, Vs, 3200);
  attn_scores<25><<<dim3(8, 128), blk, 0, stream>>>(Qs, Ks, Ps);
  attn_out<25><<<dim3(8, 128), blk, 0, stream>>>(Ps, Vs, attns);
  gemm512<<<dim3(8, 50), blk, 0, stream>>>(attns, Wo_s, bo_s, tmp, 3200);
  add_ln<<<3200, 128, 0, stream>>>(x, tmp, g1, b1, x1);
  // ---- cross attention ----
  gemm512<<<dim3(8, 50), blk, 0, stream>>>(x1, Wq_c, bq_c, Qc, 3200);
  gemm512<<<dim3(8, 192), blk, 0, stream>>>(cross, Wk_c, bk_c, Kc, 12288);
  gemm512<<<dim3(8, 192), blk, 0, stream>>>(cross, Wv_c, bv_c, Vc, 12288);
  attn_scores<96><<<dim3(8, 128), blk, 0, stream>>>(Qc, Kc, Pc);
  attn_out<96><<<dim3(8, 128), blk, 0, stream>>>(Pc, Vc, attnc);
  gemm512<<<dim3(8, 50), blk, 0, stream>>>(attnc, Wo_c, bo_c, tmp2, 3200);
  add_ln<<<3200, 128, 0, stream>>>(x1, tmp2, g2, b2, x2);
  // ---- LSTM over feature axis ----
  transpose_ld<<<128, 256, 0, stream>>>(x2, y0b);
  lstm_pipeline<<<NLAY * NGRP, 256, 0, stream>>>(y0b, youtb, ringb, ctr, ctr + 512,
                                                 Wih, Whh, bih, bhh);
  // ---- pointwise conv over channels + final LN ----
  transpose_dl<<<128, 256, 0, stream>>>(youtb, ytb);
  transpose_sq<<<512, 256, 0, stream>>>(Wc, WcT);
  gemm512<<<dim3(8, 50), blk, 0, stream>>>(ytb, WcT, bc, fy, 3200);
  add_ln<<<3200, 128, 0, stream>>>(x2, fy, g3, b3, out);
}

// Round 3
// 1645.854 us; speedup vs baseline: 3.0535x; 3.0535x over previous
//
#include <hip/hip_runtime.h>

// =====================================================================
// DecoderLayer: selfMHA -> LN -> crossMHA -> LN -> 32xLSTM(pipelined)
//               -> pointwise conv -> LN
// Round 3: LSTM handoff rebuilt fence-free (relaxed agent atomics through
//          MALL; no L2 wbl2/inv), spill fixed via amdgpu_waves_per_eu(2,2).
// =====================================================================

#define EPS_LN 1e-5f

// ---------------- fp32 tiled GEMM: C[M,512] = A[M,512]@B[512,512]+bias ----
__global__ __launch_bounds__(256)
void gemm512(const float* __restrict__ A, const float* __restrict__ B,
             const float* __restrict__ bias, float* __restrict__ C, int M) {
  __shared__ float As[16][68];
  __shared__ float Bs[16][68];
  const int t  = threadIdx.x;
  const int tx = t & 15, ty = t >> 4;
  const int row0 = blockIdx.y * 64;
  const int col0 = blockIdx.x * 64;
  float acc[4][4] = {};
  for (int k0 = 0; k0 < 512; k0 += 16) {
#pragma unroll
    for (int i = 0; i < 4; i++) {
      int idx = t + i * 256;
      int m  = idx >> 4, kk = idx & 15;
      As[kk][m] = A[(row0 + m) * 512 + k0 + kk];
      int kb = idx >> 6, n = idx & 63;
      Bs[kb][n] = B[(k0 + kb) * 512 + col0 + n];
    }
    __syncthreads();
#pragma unroll
    for (int kk = 0; kk < 16; kk++) {
      float4 a4 = *(const float4*)&As[kk][ty * 4];
      float4 b4 = *(const float4*)&Bs[kk][tx * 4];
      float av[4] = {a4.x, a4.y, a4.z, a4.w};
      float bv[4] = {b4.x, b4.y, b4.z, b4.w};
#pragma unroll
      for (int i = 0; i < 4; i++)
#pragma unroll
        for (int j = 0; j < 4; j++) acc[i][j] += av[i] * bv[j];
    }
    __syncthreads();
  }
  float4 bias4 = *(const float4*)&bias[col0 + tx * 4];
#pragma unroll
  for (int i = 0; i < 4; i++) {
    int gr = row0 + ty * 4 + i;
    if (gr < M) {
      float4 o = make_float4(acc[i][0] + bias4.x, acc[i][1] + bias4.y,
                             acc[i][2] + bias4.z, acc[i][3] + bias4.w);
      *(float4*)&C[gr * 512 + col0 + tx * 4] = o;
    }
  }
}

// ---------------- attention: scores then softmax+PV, per (b,h) -----------
template <int S>
__global__ __launch_bounds__(256)
void attn_scores(const float* __restrict__ Q, const float* __restrict__ K,
                 float* __restrict__ P) {
  __shared__ float Qs[25][64];
  __shared__ float Ks[S][65];
  const int h = blockIdx.x, b = blockIdx.y, t = threadIdx.x;
  for (int idx = t; idx < 25 * 64; idx += 256) {
    int l = idx >> 6, e = idx & 63;
    Qs[l][e] = Q[(b * 25 + l) * 512 + h * 64 + e];
  }
  for (int idx = t; idx < S * 64; idx += 256) {
    int s = idx >> 6, e = idx & 63;
    Ks[s][e] = K[(b * S + s) * 512 + h * 64 + e];
  }
  __syncthreads();
  float* Pb = P + (size_t)(b * 8 + h) * 25 * S;
  for (int idx = t; idx < 25 * S; idx += 256) {
    int l = idx / S, s = idx % S;
    float acc = 0.f;
#pragma unroll
    for (int e = 0; e < 64; e++) acc += Qs[l][e] * Ks[s][e];
    Pb[idx] = acc * 0.125f;
  }
}

template <int S>
__global__ __launch_bounds__(256)
void attn_out(const float* __restrict__ P, const float* __restrict__ V,
              float* __restrict__ O) {
  __shared__ float Ps[25][S];
  __shared__ float Vs[S][64];
  const int h = blockIdx.x, b = blockIdx.y, t = threadIdx.x;
  const float* Pb = P + (size_t)(b * 8 + h) * 25 * S;
  for (int idx = t; idx < 25 * S; idx += 256) Ps[idx / S][idx % S] = Pb[idx];
  for (int idx = t; idx < S * 64; idx += 256) {
    int s = idx >> 6, e = idx & 63;
    Vs[s][e] = V[(b * S + s) * 512 + h * 64 + e];
  }
  __syncthreads();
  if (t < 25) {
    float mx = -1e30f;
    for (int s = 0; s < S; s++) mx = fmaxf(mx, Ps[t][s]);
    float sum = 0.f;
    for (int s = 0; s < S; s++) { float p = __expf(Ps[t][s] - mx); Ps[t][s] = p; sum += p; }
    float r = 1.f / sum;
    for (int s = 0; s < S; s++) Ps[t][s] *= r;
  }
  __syncthreads();
  for (int idx = t; idx < 25 * 64; idx += 256) {
    int l = idx >> 6, e = idx & 63;
    float acc = 0.f;
    for (int s = 0; s < S; s++) acc += Ps[l][s] * Vs[s][e];
    O[(b * 25 + l) * 512 + h * 64 + e] = acc;
  }
}

// ---------------- fused residual-add + LayerNorm (rows of 512) -----------
__global__ __launch_bounds__(128)
void add_ln(const float* __restrict__ a, const float* __restrict__ b,
            const float* __restrict__ gw, const float* __restrict__ bw,
            float* __restrict__ out) {
  const int row = blockIdx.x, t = threadIdx.x;
  float4 va = ((const float4*)(a + (size_t)row * 512))[t];
  float4 vb = ((const float4*)(b + (size_t)row * 512))[t];
  float4 v = make_float4(va.x + vb.x, va.y + vb.y, va.z + vb.z, va.w + vb.w);
  float s = v.x + v.y + v.z + v.w;
  float q = v.x * v.x + v.y * v.y + v.z * v.z + v.w * v.w;
#pragma unroll
  for (int off = 32; off > 0; off >>= 1) {
    s += __shfl_down(s, off);
    q += __shfl_down(q, off);
  }
  __shared__ float red[4];
  if ((t & 63) == 0) { red[(t >> 6) * 2] = s; red[(t >> 6) * 2 + 1] = q; }
  __syncthreads();
  float S_ = red[0] + red[2], Q_ = red[1] + red[3];
  float mean = S_ * (1.f / 512.f);
  float var  = Q_ * (1.f / 512.f) - mean * mean;
  float inv  = rsqrtf(var + EPS_LN);
  float4 g4 = ((const float4*)gw)[t];
  float4 b4 = ((const float4*)bw)[t];
  float4 o;
  o.x = (v.x - mean) * inv * g4.x + b4.x;
  o.y = (v.y - mean) * inv * g4.y + b4.y;
  o.z = (v.z - mean) * inv * g4.z + b4.z;
  o.w = (v.w - mean) * inv * g4.w + b4.w;
  ((float4*)(out + (size_t)row * 512))[t] = o;
}

// ---------------- transposes --------------------------------------------
__global__ void transpose_ld(const float* __restrict__ in, float* __restrict__ outp) {
  const int b = blockIdx.x, t = threadIdx.x;
  for (int idx = t; idx < 512 * 25; idx += 256) {
    int d = idx / 25, l2 = idx % 25;
    outp[((size_t)b * 512 + d) * 25 + l2] = in[((size_t)b * 25 + l2) * 512 + d];
  }
}
__global__ void transpose_dl(const float* __restrict__ in, float* __restrict__ outp) {
  const int b = blockIdx.x, t = threadIdx.x;
  for (int idx = t; idx < 25 * 512; idx += 256) {
    int l2 = idx / 512, c = idx % 512;
    outp[((size_t)b * 25 + l2) * 512 + c] = in[((size_t)b * 512 + c) * 25 + l2];
  }
}
__global__ void transpose_sq(const float* __restrict__ in, float* __restrict__ outp) {
  const int c = blockIdx.x, t = threadIdx.x;
  for (int o = t; o < 512; o += 256) outp[(size_t)c * 512 + o] = in[(size_t)o * 512 + c];
}

// ---------------- pipelined 32-layer LSTM --------------------------------
// Handoff rule: ALL cross-block traffic (ring data + flags) uses RELAXED
// agent-scope atomics -> sc1 ops at the device coherence point (MALL).
// Correct across XCDs with NO acquire/release fences (no buffer_wbl2 /
// L2 invalidates in the hot loop). Ordering: producer drains vmcnt(0)
// per-wave + __syncthreads() BEFORE t0 publishes the flag; consumer's
// data loads are control-dependent on the flag poll.
#define NLAY 32
#define NT   512
#define NB   128
#define NGRP 16
#define BGRP 8           // batches per group
#define CHT  8           // timesteps per chunk
#define NCHK 64          // chunks (512/8)
#define RT   64          // ring depth in timesteps
#define RCHK (RT / CHT)  // ring depth in chunks = 8

__device__ __forceinline__ int ld_rlx(int* p) {
  return __hip_atomic_load(p, __ATOMIC_RELAXED, __HIP_MEMORY_SCOPE_AGENT);
}
__device__ __forceinline__ void st_rlx(int* p, int v) {
  __hip_atomic_store(p, v, __ATOMIC_RELAXED, __HIP_MEMORY_SCOPE_AGENT);
}
__device__ __forceinline__ float ldf_rlx(const float* p) {
  return __hip_atomic_load(p, __ATOMIC_RELAXED, __HIP_MEMORY_SCOPE_AGENT);
}
__device__ __forceinline__ void stf_rlx(float* p, float v) {
  __hip_atomic_store(p, v, __ATOMIC_RELAXED, __HIP_MEMORY_SCOPE_AGENT);
}
__device__ __forceinline__ float tanh_fast(float x) {
  return 1.f - 2.f / (1.f + __expf(2.f * x));
}

__global__ __launch_bounds__(256) __attribute__((amdgpu_waves_per_eu(2, 2)))
void lstm_pipeline(const float* __restrict__ y0, float* __restrict__ yout,
                   float* __restrict__ ring, int* __restrict__ prod,
                   int* __restrict__ cons,
                   const float* __restrict__ Wih, const float* __restrict__ Whh,
                   const float* __restrict__ bih, const float* __restrict__ bhh) {
  const int l = blockIdx.x / NGRP;
  const int g = blockIdx.x % NGRP;
  const int t = threadIdx.x;
  const int u  = t & 31;           // unit 0..24 active
  const int bi = t >> 5;           // batch-in-group 0..7
  const bool active = (u < 25);

  __shared__ float xbuf[CHT][BGRP][28];   // step inputs, k padded to 28
  __shared__ float hbuf[2][BGRP][28];     // double-buffered h

  // ---- per-thread register weights: rows {u,25+u,50+u,75+u} of Wih/Whh ----
  // amdgpu_waves_per_eu(2,2): RA targets exactly 2 waves/EU -> 256 VGPR
  // budget -> 200 weight floats live in registers, NO scratch spill.
  float wih[4][25], whh[4][25];
  float bias_r[4];
  float c_reg = 0.f;
  if (active) {
#pragma unroll
    for (int j = 0; j < 4; j++) {
      const float* wi = &Wih[((size_t)l * 100 + j * 25 + u) * 25];
      const float* wh = &Whh[((size_t)l * 100 + j * 25 + u) * 25];
#pragma unroll
      for (int k = 0; k < 25; k++) { wih[j][k] = wi[k]; whh[j][k] = wh[k]; }
      bias_r[j] = bih[l * 100 + j * 25 + u] + bhh[l * 100 + j * 25 + u];
    }
  }
  for (int idx = t; idx < 2 * BGRP * 28; idx += 256) (&hbuf[0][0][0])[idx] = 0.f;
  __syncthreads();

  // per-thread ring output base (active threads, l < 31)
  float* ring_out = ring + (((size_t)l * NB + g * BGRP + bi) * RT) * 25 + u;
  float* yout_out = yout + ((size_t)(g * BGRP + bi) * NT) * 25 + u;

  for (int n = 0; n < NCHK; n++) {
    if (t == 0) {
      if (l > 0) {                        // wait for input chunk n
        int* p = &prod[(l - 1) * NGRP + g];
        while (ld_rlx(p) < n + 1) __builtin_amdgcn_s_sleep(1);
      }
      if (l < NLAY - 1 && n >= RCHK) {    // wait for ring slots to free
        int* p = &cons[(l + 1) * NGRP + g];
        while (ld_rlx(p) < n - RCHK + 1) __builtin_amdgcn_s_sleep(1);
      }
    }
    __syncthreads();
    // stage chunk input into LDS (8 steps x 8 batches x 25)
    for (int idx = t; idx < CHT * BGRP * 25; idx += 256) {
      int tc = idx / (BGRP * 25);
      int r  = idx % (BGRP * 25);
      int b2 = r / 25, k = r % 25;
      int tg = n * CHT + tc;
      int b  = g * BGRP + b2;
      float v;
      if (l == 0)
        v = y0[((size_t)b * NT + tg) * 25 + k];
      else
        v = ldf_rlx(&ring[(((size_t)(l - 1) * NB + b) * RT + (tg & (RT - 1))) * 25 + k]);
      xbuf[tc][b2][k] = v;
    }
    __syncthreads();                      // staging loads complete block-wide
    if (t == 0 && l > 0) st_rlx(&cons[l * NGRP + g], n + 1);

    for (int tc = 0; tc < CHT; tc++) {
      const int tg = n * CHT + tc;
      const int p  = tg & 1;
      if (active) {
        float a0 = bias_r[0], a1 = bias_r[1], a2 = bias_r[2], a3 = bias_r[3];
        const float4* xp = (const float4*)&xbuf[tc][bi][0];
        const float4* hp = (const float4*)&hbuf[p][bi][0];
#pragma unroll
        for (int kk = 0; kk < 7; kk++) {
          float4 xv = xp[kk];
#pragma unroll
          for (int c4 = 0; c4 < 4; c4++) {
            int k = kk * 4 + c4;
            if (k < 25) {
              float xs = (&xv.x)[c4];
              a0 += wih[0][k] * xs; a1 += wih[1][k] * xs;
              a2 += wih[2][k] * xs; a3 += wih[3][k] * xs;
            }
          }
        }
#pragma unroll
        for (int kk = 0; kk < 7; kk++) {
          float4 hv = hp[kk];
#pragma unroll
          for (int c4 = 0; c4 < 4; c4++) {
            int k = kk * 4 + c4;
            if (k < 25) {
              float hs = (&hv.x)[c4];
              a0 += whh[0][k] * hs; a1 += whh[1][k] * hs;
              a2 += whh[2][k] * hs; a3 += whh[3][k] * hs;
            }
          }
        }
        float si = 1.f / (1.f + __expf(-a0));
        float sf = 1.f / (1.f + __expf(-a1));
        float so = 1.f / (1.f + __expf(-a3));
        c_reg = sf * c_reg + si * tanh_fast(a2);
        float h = so * tanh_fast(c_reg);
        hbuf[p ^ 1][bi][u] = h;
        if (l == NLAY - 1)
          yout_out[(size_t)tg * 25] = h;              // normal store (kernel-boundary coherent)
        else
          stf_rlx(&ring_out[(size_t)(tg & (RT - 1)) * 25], h);  // sc1 -> MALL
      }
      __syncthreads();
    }
    // ensure every wave's ring stores reached the coherence point before
    // t0 publishes the chunk flag (syncthreads' pre-barrier drain + belt
    // and suspenders explicit drain).
    asm volatile("s_waitcnt vmcnt(0)" ::: "memory");
    __syncthreads();
    if (t == 0 && l < NLAY - 1) st_rlx(&prod[l * NGRP + g], n + 1);
  }
}

// =====================================================================
extern "C" void kernel_launch(void* const* d_in, const int* in_sizes, int n_in,
                              void* d_out, int out_size, void* d_ws, size_t ws_size,
                              hipStream_t stream) {
  const float* x     = (const float*)d_in[0];
  const float* cross = (const float*)d_in[1];
  const float* Wq_s = (const float*)d_in[2];  const float* bq_s = (const float*)d_in[3];
  const float* Wk_s = (const float*)d_in[4];  const float* bk_s = (const float*)d_in[5];
  const float* Wv_s = (const float*)d_in[6];  const float* bv_s = (const float*)d_in[7];
  const float* Wo_s = (const float*)d_in[8];  const float* bo_s = (const float*)d_in[9];
  const float* Wq_c = (const float*)d_in[10]; const float* bq_c = (const float*)d_in[11];
  const float* Wk_c = (const float*)d_in[12]; const float* bk_c = (const float*)d_in[13];
  const float* Wv_c = (const float*)d_in[14]; const float* bv_c = (const float*)d_in[15];
  const float* Wo_c = (const float*)d_in[16]; const float* bo_c = (const float*)d_in[17];
  const float* g1 = (const float*)d_in[18]; const float* b1 = (const float*)d_in[19];
  const float* g2 = (const float*)d_in[20]; const float* b2 = (const float*)d_in[21];
  const float* g3 = (const float*)d_in[22]; const float* b3 = (const float*)d_in[23];
  const float* Wih = (const float*)d_in[24];
  const float* Whh = (const float*)d_in[25];
  const float* bih = (const float*)d_in[26];
  const float* bhh = (const float*)d_in[27];
  const float* Wc  = (const float*)d_in[28]; const float* bc = (const float*)d_in[29];
  float* out = (float*)d_out;
  float* ws  = (float*)d_ws;

  // ---- workspace layout (floats), liveness-based reuse ----
  constexpr size_t A = 1638400;    // 3200*512
  constexpr size_t Cc = 6291456;   // 12288*512
  float* x1    = ws;
  float* Qc    = ws + A;
  float* Kc    = ws + 2 * A;
  float* Vc    = ws + 2 * A + Cc;
  float* attnc = ws + 2 * A + 2 * Cc;
  float* Pc    = attnc + A;
  int*   ctr   = (int*)(Pc + 2457600);          // 1024 ints (prod|cons)
  // self-attention phase aliases
  float* Qs    = ws + 2 * A;
  float* Ks    = ws + 3 * A;
  float* Vs    = ws + 4 * A;
  float* attns = ws + 5 * A;
  float* tmp   = ws + 6 * A;
  float* Ps    = ws + 7 * A;
  // post-cross aliases
  float* tmp2  = ws + 2 * A;
  float* x2    = ws + 3 * A;
  float* y0b   = ws + 4 * A;
  float* youtb = ws + 5 * A;
  float* ringb = ws + 6 * A;       // 31*128*64*25 = 6,348,800 floats
  float* ytb   = ws + 2 * A;
  float* WcT   = ws + 6 * A;
  float* fy    = ws + 7 * A;

  hipMemsetAsync(ctr, 0, 1024 * sizeof(int), stream);

  dim3 blk(256);
  // ---- self attention ----
  gemm512<<<dim3(8, 50), blk, 0, stream>>>(x, Wq_s, bq_s, Qs, 3200);
  gemm512<<<dim3(8, 50), blk, 0, stream>>>(x, Wk_s, bk_s, Ks, 3200);
  gemm512<<<dim3(8, 50), blk, 0, stream>>>(x, Wv_s, bv_s, Vs, 3200);
  attn_scores<25><<<dim3(8, 128), blk, 0, stream>>>(Qs, Ks, Ps);
  attn_out<25><<<dim3(8, 128), blk, 0, stream>>>(Ps, Vs, attns);
  gemm512<<<dim3(8, 50), blk, 0, stream>>>(attns, Wo_s, bo_s, tmp, 3200);
  add_ln<<<3200, 128, 0, stream>>>(x, tmp, g1, b1, x1);
  // ---- cross attention ----
  gemm512<<<dim3(8, 50), blk, 0, stream>>>(x1, Wq_c, bq_c, Qc, 3200);
  gemm512<<<dim3(8, 192), blk, 0, stream>>>(cross, Wk_c, bk_c, Kc, 12288);
  gemm512<<<dim3(8, 192), blk, 0, stream>>>(cross, Wv_c, bv_c, Vc, 12288);
  attn_scores<96><<<dim3(8, 128), blk, 0, stream>>>(Qc, Kc, Pc);
  attn_out<96><<<dim3(8, 128), blk, 0, stream>>>(Pc, Vc, attnc);
  gemm512<<<dim3(8, 50), blk, 0, stream>>>(attnc, Wo_c, bo_c, tmp2, 3200);
  add_ln<<<3200, 128, 0, stream>>>(x1, tmp2, g2, b2, x2);
  // ---- LSTM over feature axis ----
  transpose_ld<<<128, 256, 0, stream>>>(x2, y0b);
  lstm_pipeline<<<NLAY * NGRP, 256, 0, stream>>>(y0b, youtb, ringb, ctr, ctr + 512,
                                                 Wih, Whh, bih, bhh);
  // ---- pointwise conv over channels + final LN ----
  transpose_dl<<<128, 256, 0, stream>>>(youtb, ytb);
  transpose_sq<<<512, 256, 0, stream>>>(Wc, WcT);
  gemm512<<<dim3(8, 50), blk, 0, stream>>>(ytb, WcT, bc, fy, 3200);
  add_ln<<<3200, 128, 0, stream>>>(x2, fy, g3, b3, out);
}

// Round 4
// 1263.964 us; speedup vs baseline: 3.9761x; 1.3021x over previous
//
#include <hip/hip_runtime.h>

// =====================================================================
// DecoderLayer: selfMHA -> LN -> crossMHA -> LN -> 32xLSTM(pipelined)
//               -> pointwise conv -> LN
// Round 4: (a) LSTM datapath packed f16: x/h in LDS as f16 (4 vec reads vs
//          7), weights as 104 packed-half2 VGPRs, v_dot2_f32_f16 gates with
//          fp32 accumulate; c/ring/flags stay fp32.
//          (b) all dense GEMMs -> f16 MFMA (16x16x32), fp32 accum/store.
// =====================================================================

#define EPS_LN 1e-5f

typedef _Float16 h2v __attribute__((ext_vector_type(2)));
typedef _Float16 h8v __attribute__((ext_vector_type(8)));
typedef float    f4v __attribute__((ext_vector_type(4)));

#if defined(__has_builtin)
#if __has_builtin(__builtin_amdgcn_fdot2)
#define HAVE_FDOT2 1
#endif
#endif

__device__ __forceinline__ float fdot2(h2v a, h2v b, float c) {
#ifdef HAVE_FDOT2
  return __builtin_amdgcn_fdot2(a, b, c, false);
#else
  return c + (float)a.x * (float)b.x + (float)a.y * (float)b.y;
#endif
}
__device__ __forceinline__ h2v bch2(unsigned int u) {
  return __builtin_bit_cast(h2v, u);
}

// ---------------- f16 MFMA GEMM: C[M,512] = A16[M,512] @ B + bias ---------
// BT16 is B pre-transposed to [n][k] layout (k contiguous), f16.
__global__ __launch_bounds__(256)
void gemm_f16(const _Float16* __restrict__ A16, const _Float16* __restrict__ BT16,
              const float* __restrict__ bias, float* __restrict__ C, int M) {
  // LDS rows padded to 40 halves (80 B): 16B-aligned rows, 2-way banks (free)
  __shared__ _Float16 Asld[64 * 40];
  __shared__ _Float16 Bsld[64 * 40];
  const int t = threadIdx.x;
  const int m0 = blockIdx.y * 64;
  const int n0 = blockIdx.x * 64;
  const int r = t >> 2, q = t & 3;         // staging: row 0..63, quad 0..3
  const int w = t >> 6;                    // wave 0..3 -> m-strip w*16
  const int lane = t & 63;
  const int lm = lane & 15, q8 = lane >> 4;

  f4v acc[4] = {};
  for (int k0 = 0; k0 < 512; k0 += 32) {
    __syncthreads();
    *(uint4*)&Asld[r * 40 + q * 8] = *(const uint4*)&A16[(size_t)(m0 + r) * 512 + k0 + q * 8];
    *(uint4*)&Bsld[r * 40 + q * 8] = *(const uint4*)&BT16[(size_t)(n0 + r) * 512 + k0 + q * 8];
    __syncthreads();
    h8v a = *(const h8v*)&Asld[(w * 16 + lm) * 40 + q8 * 8];
#pragma unroll
    for (int nt = 0; nt < 4; nt++) {
      h8v b = *(const h8v*)&Bsld[(nt * 16 + lm) * 40 + q8 * 8];
      acc[nt] = __builtin_amdgcn_mfma_f32_16x16x32_f16(a, b, acc[nt], 0, 0, 0);
    }
  }
  // C/D layout: col = lane&15 (+16*nt), row = (lane>>4)*4 + reg  [m89-verified]
#pragma unroll
  for (int nt = 0; nt < 4; nt++) {
    int gn = n0 + nt * 16 + lm;
    float bv = bias[gn];
#pragma unroll
    for (int rg = 0; rg < 4; rg++) {
      int gm = m0 + w * 16 + q8 * 4 + rg;
      C[(size_t)gm * 512 + gn] = acc[nt][rg] + bv;
    }
  }
}

// ---------------- conversion / transpose preps ---------------------------
__global__ void cvt16(const float* __restrict__ in, _Float16* __restrict__ outp, int n) {
  int i = blockIdx.x * blockDim.x + threadIdx.x;
  int stride = gridDim.x * blockDim.x;
  for (; i < n; i += stride) outp[i] = (_Float16)in[i];
}

// W[k=512][n=512] fp32 -> WT16[n][k] f16 (tiled, coalesced both sides)
__global__ __launch_bounds__(256)
void transpose_cvt(const float* __restrict__ in, _Float16* __restrict__ outp) {
  __shared__ float tile[32][33];
  const int tx = threadIdx.x & 31, ty = threadIdx.x >> 5;
  const int bx = blockIdx.x, by = blockIdx.y;
#pragma unroll
  for (int i = 0; i < 4; i++)
    tile[ty + i * 8][tx] = in[(size_t)(by * 32 + ty + i * 8) * 512 + bx * 32 + tx];
  __syncthreads();
#pragma unroll
  for (int i = 0; i < 4; i++)
    outp[(size_t)(bx * 32 + ty + i * 8) * 512 + by * 32 + tx] = (_Float16)tile[tx][ty + i * 8];
}

// ---------------- attention: scores then softmax+PV, per (b,h) -----------
template <int S>
__global__ __launch_bounds__(256)
void attn_scores(const float* __restrict__ Q, const float* __restrict__ K,
                 float* __restrict__ P) {
  __shared__ float Qs[25][64];
  __shared__ float Ks[S][65];
  const int h = blockIdx.x, b = blockIdx.y, t = threadIdx.x;
  for (int idx = t; idx < 25 * 64; idx += 256) {
    int l = idx >> 6, e = idx & 63;
    Qs[l][e] = Q[(b * 25 + l) * 512 + h * 64 + e];
  }
  for (int idx = t; idx < S * 64; idx += 256) {
    int s = idx >> 6, e = idx & 63;
    Ks[s][e] = K[(b * S + s) * 512 + h * 64 + e];
  }
  __syncthreads();
  float* Pb = P + (size_t)(b * 8 + h) * 25 * S;
  for (int idx = t; idx < 25 * S; idx += 256) {
    int l = idx / S, s = idx % S;
    float acc = 0.f;
#pragma unroll
    for (int e = 0; e < 64; e++) acc += Qs[l][e] * Ks[s][e];
    Pb[idx] = acc * 0.125f;
  }
}

template <int S>
__global__ __launch_bounds__(256)
void attn_out(const float* __restrict__ P, const float* __restrict__ V,
              float* __restrict__ O) {
  __shared__ float Ps[25][S];
  __shared__ float Vs[S][64];
  const int h = blockIdx.x, b = blockIdx.y, t = threadIdx.x;
  const float* Pb = P + (size_t)(b * 8 + h) * 25 * S;
  for (int idx = t; idx < 25 * S; idx += 256) Ps[idx / S][idx % S] = Pb[idx];
  for (int idx = t; idx < S * 64; idx += 256) {
    int s = idx >> 6, e = idx & 63;
    Vs[s][e] = V[(b * S + s) * 512 + h * 64 + e];
  }
  __syncthreads();
  if (t < 25) {
    float mx = -1e30f;
    for (int s = 0; s < S; s++) mx = fmaxf(mx, Ps[t][s]);
    float sum = 0.f;
    for (int s = 0; s < S; s++) { float p = __expf(Ps[t][s] - mx); Ps[t][s] = p; sum += p; }
    float r = 1.f / sum;
    for (int s = 0; s < S; s++) Ps[t][s] *= r;
  }
  __syncthreads();
  for (int idx = t; idx < 25 * 64; idx += 256) {
    int l = idx >> 6, e = idx & 63;
    float acc = 0.f;
    for (int s = 0; s < S; s++) acc += Ps[l][s] * Vs[s][e];
    O[(b * 25 + l) * 512 + h * 64 + e] = acc;
  }
}

// ---------------- fused residual-add + LayerNorm (rows of 512) -----------
__global__ __launch_bounds__(128)
void add_ln(const float* __restrict__ a, const float* __restrict__ b,
            const float* __restrict__ gw, const float* __restrict__ bw,
            float* __restrict__ out) {
  const int row = blockIdx.x, t = threadIdx.x;
  float4 va = ((const float4*)(a + (size_t)row * 512))[t];
  float4 vb = ((const float4*)(b + (size_t)row * 512))[t];
  float4 v = make_float4(va.x + vb.x, va.y + vb.y, va.z + vb.z, va.w + vb.w);
  float s = v.x + v.y + v.z + v.w;
  float q = v.x * v.x + v.y * v.y + v.z * v.z + v.w * v.w;
#pragma unroll
  for (int off = 32; off > 0; off >>= 1) {
    s += __shfl_down(s, off);
    q += __shfl_down(q, off);
  }
  __shared__ float red[4];
  if ((t & 63) == 0) { red[(t >> 6) * 2] = s; red[(t >> 6) * 2 + 1] = q; }
  __syncthreads();
  float S_ = red[0] + red[2], Q_ = red[1] + red[3];
  float mean = S_ * (1.f / 512.f);
  float var  = Q_ * (1.f / 512.f) - mean * mean;
  float inv  = rsqrtf(var + EPS_LN);
  float4 g4 = ((const float4*)gw)[t];
  float4 b4 = ((const float4*)bw)[t];
  float4 o;
  o.x = (v.x - mean) * inv * g4.x + b4.x;
  o.y = (v.y - mean) * inv * g4.y + b4.y;
  o.z = (v.z - mean) * inv * g4.z + b4.z;
  o.w = (v.w - mean) * inv * g4.w + b4.w;
  ((float4*)(out + (size_t)row * 512))[t] = o;
}

// ---------------- transposes --------------------------------------------
__global__ void transpose_ld(const float* __restrict__ in, float* __restrict__ outp) {
  const int b = blockIdx.x, t = threadIdx.x;
  for (int idx = t; idx < 512 * 25; idx += 256) {
    int d = idx / 25, l2 = idx % 25;
    outp[((size_t)b * 512 + d) * 25 + l2] = in[((size_t)b * 25 + l2) * 512 + d];
  }
}
__global__ void transpose_dl_f16(const float* __restrict__ in, _Float16* __restrict__ outp) {
  const int b = blockIdx.x, t = threadIdx.x;
  for (int idx = t; idx < 25 * 512; idx += 256) {
    int l2 = idx / 512, c = idx % 512;
    outp[((size_t)b * 25 + l2) * 512 + c] = (_Float16)in[((size_t)b * 512 + c) * 25 + l2];
  }
}

// ---------------- pipelined 32-layer LSTM (f16 datapath) -----------------
// Cross-block: ring data + flags via RELAXED agent-scope atomics (MALL) as
// in R3 (proven). In-block: x/h in LDS as f16 (4 vector reads per 25-vec),
// weights as packed half2 in VGPRs, v_dot2_f32_f16 with fp32 accumulators.
#define NLAY 32
#define NT   512
#define NB   128
#define NGRP 16
#define BGRP 8
#define CHT  8
#define NCHK 64
#define RT   64
#define RCHK (RT / CHT)

__device__ __forceinline__ int ld_rlx(int* p) {
  return __hip_atomic_load(p, __ATOMIC_RELAXED, __HIP_MEMORY_SCOPE_AGENT);
}
__device__ __forceinline__ void st_rlx(int* p, int v) {
  __hip_atomic_store(p, v, __ATOMIC_RELAXED, __HIP_MEMORY_SCOPE_AGENT);
}
__device__ __forceinline__ float ldf_rlx(const float* p) {
  return __hip_atomic_load(p, __ATOMIC_RELAXED, __HIP_MEMORY_SCOPE_AGENT);
}
__device__ __forceinline__ void stf_rlx(float* p, float v) {
  __hip_atomic_store(p, v, __ATOMIC_RELAXED, __HIP_MEMORY_SCOPE_AGENT);
}
__device__ __forceinline__ float tanh_fast(float x) {
  return 1.f - 2.f / (1.f + __expf(2.f * x));
}

__global__ __launch_bounds__(256) __attribute__((amdgpu_waves_per_eu(2, 2)))
void lstm_pipeline(const float* __restrict__ y0, float* __restrict__ yout,
                   float* __restrict__ ring, int* __restrict__ prod,
                   int* __restrict__ cons,
                   const float* __restrict__ Wih, const float* __restrict__ Whh,
                   const float* __restrict__ bih, const float* __restrict__ bhh) {
  const int l = blockIdx.x / NGRP;
  const int g = blockIdx.x % NGRP;
  const int t = threadIdx.x;
  const int u  = t & 31;
  const int bi = t >> 5;
  const bool active = (u < 25);

  __shared__ _Float16 xbuf[CHT][BGRP][32];  // rows 64 B (16B-aligned vec reads)
  __shared__ _Float16 hbuf[2][BGRP][32];

  // ---- weights as packed half2: rows {u,25+u,50+u,75+u}, 104 VGPRs ------
  h2v wih2[4][13], whh2[4][13];
  float bias_r[4];
  float c_reg = 0.f;
  {
    const int uc = active ? u : 24;       // uniform code path, clamped idx
#pragma unroll
    for (int j = 0; j < 4; j++) {
      const float* wi = &Wih[((size_t)l * 100 + j * 25 + uc) * 25];
      const float* wh = &Whh[((size_t)l * 100 + j * 25 + uc) * 25];
#pragma unroll
      for (int k = 0; k < 13; k++) {
        float alo = wi[2 * k], ahi = (2 * k + 1 < 25) ? wi[2 * k + 1] : 0.f;
        float blo = wh[2 * k], bhi = (2 * k + 1 < 25) ? wh[2 * k + 1] : 0.f;
        wih2[j][k] = h2v{(_Float16)alo, (_Float16)ahi};
        whh2[j][k] = h2v{(_Float16)blo, (_Float16)bhi};
      }
      bias_r[j] = bih[l * 100 + j * 25 + uc] + bhh[l * 100 + j * 25 + uc];
    }
  }
  // zero ALL of xbuf/hbuf once: pads [25..31] must stay 0 (0xAA poison = NaN)
  for (int idx = t; idx < CHT * BGRP * 32; idx += 256) (&xbuf[0][0][0])[idx] = (_Float16)0.f;
  for (int idx = t; idx < 2 * BGRP * 32; idx += 256) (&hbuf[0][0][0])[idx] = (_Float16)0.f;
  __syncthreads();

  float* ring_out = ring + (((size_t)l * NB + g * BGRP + bi) * RT) * 25 + u;
  float* yout_out = yout + ((size_t)(g * BGRP + bi) * NT) * 25 + u;

  for (int n = 0; n < NCHK; n++) {
    if (t == 0) {
      if (l > 0) {
        int* p = &prod[(l - 1) * NGRP + g];
        while (ld_rlx(p) < n + 1) __builtin_amdgcn_s_sleep(1);
      }
      if (l < NLAY - 1 && n >= RCHK) {
        int* p = &cons[(l + 1) * NGRP + g];
        while (ld_rlx(p) < n - RCHK + 1) __builtin_amdgcn_s_sleep(1);
      }
    }
    __syncthreads();
    for (int idx = t; idx < CHT * BGRP * 25; idx += 256) {
      int tc = idx / (BGRP * 25);
      int r  = idx % (BGRP * 25);
      int b2 = r / 25, k = r % 25;
      int tg = n * CHT + tc;
      int b  = g * BGRP + b2;
      float v;
      if (l == 0)
        v = y0[((size_t)b * NT + tg) * 25 + k];
      else
        v = ldf_rlx(&ring[(((size_t)(l - 1) * NB + b) * RT + (tg & (RT - 1))) * 25 + k]);
      xbuf[tc][b2][k] = (_Float16)v;
    }
    __syncthreads();
    if (t == 0 && l > 0) st_rlx(&cons[l * NGRP + g], n + 1);

    for (int tc = 0; tc < CHT; tc++) {
      const int tg = n * CHT + tc;
      const int p  = tg & 1;
      if (active) {
        float a0 = bias_r[0], a1 = bias_r[1], a2 = bias_r[2], a3 = bias_r[3];
        // x vector: 13 half2 via 3x b128 + 1x b32 (rows 64B-aligned)
        const unsigned int* xr = (const unsigned int*)&xbuf[tc][bi][0];
        uint4 xa = *(const uint4*)(xr);
        uint4 xb = *(const uint4*)(xr + 4);
        uint4 xc = *(const uint4*)(xr + 8);
        unsigned int xd = xr[12];
        h2v xk[13] = {bch2(xa.x), bch2(xa.y), bch2(xa.z), bch2(xa.w),
                      bch2(xb.x), bch2(xb.y), bch2(xb.z), bch2(xb.w),
                      bch2(xc.x), bch2(xc.y), bch2(xc.z), bch2(xc.w),
                      bch2(xd)};
#pragma unroll
        for (int k = 0; k < 13; k++) {
          a0 = fdot2(wih2[0][k], xk[k], a0);
          a1 = fdot2(wih2[1][k], xk[k], a1);
          a2 = fdot2(wih2[2][k], xk[k], a2);
          a3 = fdot2(wih2[3][k], xk[k], a3);
        }
        const unsigned int* hr = (const unsigned int*)&hbuf[p][bi][0];
        uint4 ha = *(const uint4*)(hr);
        uint4 hb = *(const uint4*)(hr + 4);
        uint4 hc = *(const uint4*)(hr + 8);
        unsigned int hd = hr[12];
        h2v hk[13] = {bch2(ha.x), bch2(ha.y), bch2(ha.z), bch2(ha.w),
                      bch2(hb.x), bch2(hb.y), bch2(hb.z), bch2(hb.w),
                      bch2(hc.x), bch2(hc.y), bch2(hc.z), bch2(hc.w),
                      bch2(hd)};
#pragma unroll
        for (int k = 0; k < 13; k++) {
          a0 = fdot2(whh2[0][k], hk[k], a0);
          a1 = fdot2(whh2[1][k], hk[k], a1);
          a2 = fdot2(whh2[2][k], hk[k], a2);
          a3 = fdot2(whh2[3][k], hk[k], a3);
        }
        float si = 1.f / (1.f + __expf(-a0));
        float sf = 1.f / (1.f + __expf(-a1));
        float so = 1.f / (1.f + __expf(-a3));
        c_reg = sf * c_reg + si * tanh_fast(a2);
        float h = so * tanh_fast(c_reg);
        hbuf[p ^ 1][bi][u] = (_Float16)h;
        if (l == NLAY - 1)
          yout_out[(size_t)tg * 25] = h;
        else
          stf_rlx(&ring_out[(size_t)(tg & (RT - 1)) * 25], h);
      }
      __syncthreads();
    }
    asm volatile("s_waitcnt vmcnt(0)" ::: "memory");
    __syncthreads();
    if (t == 0 && l < NLAY - 1) st_rlx(&prod[l * NGRP + g], n + 1);
  }
}

// =====================================================================
extern "C" void kernel_launch(void* const* d_in, const int* in_sizes, int n_in,
                              void* d_out, int out_size, void* d_ws, size_t ws_size,
                              hipStream_t stream) {
  const float* x     = (const float*)d_in[0];
  const float* cross = (const float*)d_in[1];
  const float* Wq_s = (const float*)d_in[2];  const float* bq_s = (const float*)d_in[3];
  const float* Wk_s = (const float*)d_in[4];  const float* bk_s = (const float*)d_in[5];
  const float* Wv_s = (const float*)d_in[6];  const float* bv_s = (const float*)d_in[7];
  const float* Wo_s = (const float*)d_in[8];  const float* bo_s = (const float*)d_in[9];
  const float* Wq_c = (const float*)d_in[10]; const float* bq_c = (const float*)d_in[11];
  const float* Wk_c = (const float*)d_in[12]; const float* bk_c = (const float*)d_in[13];
  const float* Wv_c = (const float*)d_in[14]; const float* bv_c = (const float*)d_in[15];
  const float* Wo_c = (const float*)d_in[16]; const float* bo_c = (const float*)d_in[17];
  const float* g1 = (const float*)d_in[18]; const float* b1 = (const float*)d_in[19];
  const float* g2 = (const float*)d_in[20]; const float* b2 = (const float*)d_in[21];
  const float* g3 = (const float*)d_in[22]; const float* b3 = (const float*)d_in[23];
  const float* Wih = (const float*)d_in[24];
  const float* Whh = (const float*)d_in[25];
  const float* bih = (const float*)d_in[26];
  const float* bhh = (const float*)d_in[27];
  const float* Wc  = (const float*)d_in[28]; const float* bc = (const float*)d_in[29];
  float* out = (float*)d_out;
  float* ws  = (float*)d_ws;

  // ---- workspace (floats); time-multiplexed regions; peak ~84.7 MB ------
  constexpr size_t A  = 1638400;    // 3200*512
  constexpr size_t C6 = 6291456;    // 12288*512
  float* x1    = ws;                // 0..A
  float* Qc    = ws + A;
  // self phase
  float* Qs    = ws + 2 * A;
  float* Ks    = ws + 3 * A;
  float* Vs    = ws + 4 * A;
  float* attns = ws + 5 * A;
  float* tmp   = ws + 6 * A;
  float* Ps    = ws + 7 * A;                     // 640000
  // cross phase
  float* Kc    = ws + 2 * A;
  float* Vc    = ws + 2 * A + C6;
  float* attnc = ws + 2 * A + 2 * C6;            // 15,859,712
  float* Pc    = attnc + A;                      // 17,498,112 (+2,457,600)
  float* tmp2  = ws + 6 * A;                     // after Vc dead
  float* x2    = ws + 3 * A;
  // lstm / post
  float* y0b   = ws + 4 * A;
  float* youtb = ws + 5 * A;
  float* ringb = ws + 6 * A;                     // 6,348,800 floats
  float* fy    = ws + 5 * A;                     // after youtb dead
  // f16 arenas (time-multiplexed into dead fp32 regions)
  _Float16* cross16 = (_Float16*)attnc;          // live only pre-scores
  _Float16* act16   = (_Float16*)Pc;             // x16/attns16/x116/attnc16/ytb16
  float* WTbase = ws + 20000000;
  _Float16* WT[8];
  for (int i = 0; i < 8; i++) WT[i] = (_Float16*)(WTbase + (size_t)i * 131072);
  _Float16* Wc16 = (_Float16*)(ws + 21048576);
  int* ctr = (int*)(ws + 21179648);              // 1024 ints

  dim3 blk(256);
  // ---- prep: weight transposes+converts (once per call) ----
  const float* Wsrc[8] = {Wq_s, Wk_s, Wv_s, Wo_s, Wq_c, Wk_c, Wv_c, Wo_c};
  for (int i = 0; i < 8; i++)
    transpose_cvt<<<dim3(16, 16), blk, 0, stream>>>(Wsrc[i], WT[i]);
  cvt16<<<256, 256, 0, stream>>>(Wc, Wc16, 262144);
  hipMemsetAsync(ctr, 0, 1024 * sizeof(int), stream);

  // ---- self attention ----
  cvt16<<<2048, 256, 0, stream>>>(x, act16, (int)A);
  gemm_f16<<<dim3(8, 50), blk, 0, stream>>>(act16, WT[0], bq_s, Qs, 3200);
  gemm_f16<<<dim3(8, 50), blk, 0, stream>>>(act16, WT[1], bk_s, Ks, 3200);
  gemm_f16<<<dim3(8, 50), blk, 0, stream>>>(act16, WT[2], bv_s, Vs, 3200);
  attn_scores<25><<<dim3(8, 128), blk, 0, stream>>>(Qs, Ks, Ps);
  attn_out<25><<<dim3(8, 128), blk, 0, stream>>>(Ps, Vs, attns);
  cvt16<<<2048, 256, 0, stream>>>(attns, act16, (int)A);
  gemm_f16<<<dim3(8, 50), blk, 0, stream>>>(act16, WT[3], bo_s, tmp, 3200);
  add_ln<<<3200, 128, 0, stream>>>(x, tmp, g1, b1, x1);
  // ---- cross attention ----
  cvt16<<<2048, 256, 0, stream>>>(x1, act16, (int)A);
  gemm_f16<<<dim3(8, 50), blk, 0, stream>>>(act16, WT[4], bq_c, Qc, 3200);
  cvt16<<<4096, 256, 0, stream>>>(cross, cross16, (int)C6);
  gemm_f16<<<dim3(8, 192), blk, 0, stream>>>(cross16, WT[5], bk_c, Kc, 12288);
  gemm_f16<<<dim3(8, 192), blk, 0, stream>>>(cross16, WT[6], bv_c, Vc, 12288);
  attn_scores<96><<<dim3(8, 128), blk, 0, stream>>>(Qc, Kc, Pc);
  attn_out<96><<<dim3(8, 128), blk, 0, stream>>>(Pc, Vc, attnc);
  cvt16<<<2048, 256, 0, stream>>>(attnc, act16, (int)A);
  gemm_f16<<<dim3(8, 50), blk, 0, stream>>>(act16, WT[7], bo_c, tmp2, 3200);
  add_ln<<<3200, 128, 0, stream>>>(x1, tmp2, g2, b2, x2);
  // ---- LSTM over feature axis ----
  transpose_ld<<<128, 256, 0, stream>>>(x2, y0b);
  lstm_pipeline<<<NLAY * NGRP, 256, 0, stream>>>(y0b, youtb, ringb, ctr, ctr + 512,
                                                 Wih, Whh, bih, bhh);
  // ---- pointwise conv over channels + final LN ----
  transpose_dl_f16<<<128, 256, 0, stream>>>(youtb, act16);
  gemm_f16<<<dim3(8, 50), blk, 0, stream>>>(act16, Wc16, bc, fy, 3200);
  add_ln<<<3200, 128, 0, stream>>>(x2, fy, g3, b3, out);
}

// Round 5
// 1183.608 us; speedup vs baseline: 4.2461x; 1.0679x over previous
//
#include <hip/hip_runtime.h>

// =====================================================================
// DecoderLayer: selfMHA -> LN -> crossMHA -> LN -> 32xLSTM(pipelined)
//               -> pointwise conv -> LN
// Round 5: (a) LSTM wave-autonomous recurrence: each wave owns 2 batches,
//          h exchange intra-wave via LDS (no per-step barriers; 3/chunk).
//          (b) GEMMs stage fp32 A + convert in-LDS (all activation cvt16
//          dispatches deleted); QKV / cross-KV / weight-prep fused.
// =====================================================================

#define EPS_LN 1e-5f

typedef _Float16 h2v __attribute__((ext_vector_type(2)));
typedef _Float16 h8v __attribute__((ext_vector_type(8)));
typedef float    f4v __attribute__((ext_vector_type(4)));

#if defined(__has_builtin)
#if __has_builtin(__builtin_amdgcn_fdot2)
#define HAVE_FDOT2 1
#endif
#endif

__device__ __forceinline__ float fdot2(h2v a, h2v b, float c) {
#ifdef HAVE_FDOT2
  return __builtin_amdgcn_fdot2(a, b, c, false);
#else
  return c + (float)a.x * (float)b.x + (float)a.y * (float)b.y;
#endif
}
__device__ __forceinline__ h2v bch2(unsigned int u) {
  return __builtin_bit_cast(h2v, u);
}

// ---------------- fused weight prep: 8 transposes + 1 straight cvt -------
struct WPtrs { const float* p[9]; };

__global__ __launch_bounds__(256)
void prep_weights(WPtrs w, _Float16* __restrict__ dst) {
  __shared__ float tile[32][33];
  const int z = blockIdx.z;
  const int tx = threadIdx.x & 31, ty = threadIdx.x >> 5;
  const int bx = blockIdx.x, by = blockIdx.y;
  const float* in = w.p[z];
  _Float16* outp = dst + (size_t)z * 262144;
  if (z < 8) {   // WT[n][k] = W[k][n], f16
#pragma unroll
    for (int i = 0; i < 4; i++)
      tile[ty + i * 8][tx] = in[(size_t)(by * 32 + ty + i * 8) * 512 + bx * 32 + tx];
    __syncthreads();
#pragma unroll
    for (int i = 0; i < 4; i++)
      outp[(size_t)(bx * 32 + ty + i * 8) * 512 + by * 32 + tx] = (_Float16)tile[tx][ty + i * 8];
  } else {       // Wc is [o][c] already == BT layout; straight cvt
#pragma unroll
    for (int i = 0; i < 4; i++) {
      size_t off = (size_t)(by * 32 + ty + i * 8) * 512 + bx * 32 + tx;
      outp[off] = (_Float16)in[off];
    }
  }
}

// ---------------- f16 MFMA GEMM, fp32 A staged+converted in LDS ----------
// Up to 3 output matrices selected by blockIdx.x>>3 (fused QKV / KV).
__global__ __launch_bounds__(256)
void gemm3(const float* __restrict__ A,
           const _Float16* __restrict__ BT0, const _Float16* __restrict__ BT1,
           const _Float16* __restrict__ BT2,
           const float* __restrict__ bias0, const float* __restrict__ bias1,
           const float* __restrict__ bias2,
           float* __restrict__ C0, float* __restrict__ C1, float* __restrict__ C2,
           int M) {
  __shared__ _Float16 Asld[64 * 40];   // rows padded to 40 halves (80 B)
  __shared__ _Float16 Bsld[64 * 40];
  const int t = threadIdx.x;
  const int which = blockIdx.x >> 3;
  const int n0 = (blockIdx.x & 7) * 64;
  const int m0 = blockIdx.y * 64;
  const _Float16* BT = (which == 0) ? BT0 : (which == 1) ? BT1 : BT2;
  const float* bias  = (which == 0) ? bias0 : (which == 1) ? bias1 : bias2;
  float* C           = (which == 0) ? C0 : (which == 1) ? C1 : C2;

  const int r = t >> 2, q = t & 3;     // staging: row 0..63, 8-elem segment
  const int w = t >> 6;                // wave 0..3 -> m-strip w*16
  const int lane = t & 63;
  const int lm = lane & 15, q8 = lane >> 4;

  f4v acc[4] = {};
  for (int k0 = 0; k0 < 512; k0 += 32) {
    __syncthreads();
    float4 f0 = *(const float4*)&A[(size_t)(m0 + r) * 512 + k0 + q * 8];
    float4 f1 = *(const float4*)&A[(size_t)(m0 + r) * 512 + k0 + q * 8 + 4];
    h8v hv = {(_Float16)f0.x, (_Float16)f0.y, (_Float16)f0.z, (_Float16)f0.w,
              (_Float16)f1.x, (_Float16)f1.y, (_Float16)f1.z, (_Float16)f1.w};
    *(h8v*)&Asld[r * 40 + q * 8] = hv;
    *(uint4*)&Bsld[r * 40 + q * 8] = *(const uint4*)&BT[(size_t)(n0 + r) * 512 + k0 + q * 8];
    __syncthreads();
    h8v a = *(const h8v*)&Asld[(w * 16 + lm) * 40 + q8 * 8];
#pragma unroll
    for (int nt = 0; nt < 4; nt++) {
      h8v b = *(const h8v*)&Bsld[(nt * 16 + lm) * 40 + q8 * 8];
      acc[nt] = __builtin_amdgcn_mfma_f32_16x16x32_f16(a, b, acc[nt], 0, 0, 0);
    }
  }
  // C/D layout: col = lane&15 (+16*nt), row = (lane>>4)*4 + reg
#pragma unroll
  for (int nt = 0; nt < 4; nt++) {
    int gn = n0 + nt * 16 + lm;
    float bv = bias[gn];
#pragma unroll
    for (int rg = 0; rg < 4; rg++) {
      int gm = m0 + w * 16 + q8 * 4 + rg;
      C[(size_t)gm * 512 + gn] = acc[nt][rg] + bv;
    }
  }
}

// ---------------- attention: scores then softmax+PV, per (b,h) -----------
template <int S>
__global__ __launch_bounds__(256)
void attn_scores(const float* __restrict__ Q, const float* __restrict__ K,
                 float* __restrict__ P) {
  __shared__ float Qs[25][64];
  __shared__ float Ks[S][65];
  const int h = blockIdx.x, b = blockIdx.y, t = threadIdx.x;
  for (int idx = t; idx < 25 * 64; idx += 256) {
    int l = idx >> 6, e = idx & 63;
    Qs[l][e] = Q[(b * 25 + l) * 512 + h * 64 + e];
  }
  for (int idx = t; idx < S * 64; idx += 256) {
    int s = idx >> 6, e = idx & 63;
    Ks[s][e] = K[(b * S + s) * 512 + h * 64 + e];
  }
  __syncthreads();
  float* Pb = P + (size_t)(b * 8 + h) * 25 * S;
  for (int idx = t; idx < 25 * S; idx += 256) {
    int l = idx / S, s = idx % S;
    float acc = 0.f;
#pragma unroll
    for (int e = 0; e < 64; e++) acc += Qs[l][e] * Ks[s][e];
    Pb[idx] = acc * 0.125f;
  }
}

template <int S>
__global__ __launch_bounds__(256)
void attn_out(const float* __restrict__ P, const float* __restrict__ V,
              float* __restrict__ O) {
  __shared__ float Ps[25][S];
  __shared__ float Vs[S][64];
  const int h = blockIdx.x, b = blockIdx.y, t = threadIdx.x;
  const float* Pb = P + (size_t)(b * 8 + h) * 25 * S;
  for (int idx = t; idx < 25 * S; idx += 256) Ps[idx / S][idx % S] = Pb[idx];
  for (int idx = t; idx < S * 64; idx += 256) {
    int s = idx >> 6, e = idx & 63;
    Vs[s][e] = V[(b * S + s) * 512 + h * 64 + e];
  }
  __syncthreads();
  if (t < 25) {
    float mx = -1e30f;
    for (int s = 0; s < S; s++) mx = fmaxf(mx, Ps[t][s]);
    float sum = 0.f;
    for (int s = 0; s < S; s++) { float p = __expf(Ps[t][s] - mx); Ps[t][s] = p; sum += p; }
    float r = 1.f / sum;
    for (int s = 0; s < S; s++) Ps[t][s] *= r;
  }
  __syncthreads();
  for (int idx = t; idx < 25 * 64; idx += 256) {
    int l = idx >> 6, e = idx & 63;
    float acc = 0.f;
    for (int s = 0; s < S; s++) acc += Ps[l][s] * Vs[s][e];
    O[(b * 25 + l) * 512 + h * 64 + e] = acc;
  }
}

// ---------------- fused residual-add + LayerNorm (rows of 512) -----------
__global__ __launch_bounds__(128)
void add_ln(const float* __restrict__ a, const float* __restrict__ b,
            const float* __restrict__ gw, const float* __restrict__ bw,
            float* __restrict__ out) {
  const int row = blockIdx.x, t = threadIdx.x;
  float4 va = ((const float4*)(a + (size_t)row * 512))[t];
  float4 vb = ((const float4*)(b + (size_t)row * 512))[t];
  float4 v = make_float4(va.x + vb.x, va.y + vb.y, va.z + vb.z, va.w + vb.w);
  float s = v.x + v.y + v.z + v.w;
  float q = v.x * v.x + v.y * v.y + v.z * v.z + v.w * v.w;
#pragma unroll
  for (int off = 32; off > 0; off >>= 1) {
    s += __shfl_down(s, off);
    q += __shfl_down(q, off);
  }
  __shared__ float red[4];
  if ((t & 63) == 0) { red[(t >> 6) * 2] = s; red[(t >> 6) * 2 + 1] = q; }
  __syncthreads();
  float S_ = red[0] + red[2], Q_ = red[1] + red[3];
  float mean = S_ * (1.f / 512.f);
  float var  = Q_ * (1.f / 512.f) - mean * mean;
  float inv  = rsqrtf(var + EPS_LN);
  float4 g4 = ((const float4*)gw)[t];
  float4 b4 = ((const float4*)bw)[t];
  float4 o;
  o.x = (v.x - mean) * inv * g4.x + b4.x;
  o.y = (v.y - mean) * inv * g4.y + b4.y;
  o.z = (v.z - mean) * inv * g4.z + b4.z;
  o.w = (v.w - mean) * inv * g4.w + b4.w;
  ((float4*)(out + (size_t)row * 512))[t] = o;
}

// ---------------- transposes --------------------------------------------
__global__ void transpose_ld(const float* __restrict__ in, float* __restrict__ outp) {
  const int b = blockIdx.x, t = threadIdx.x;
  for (int idx = t; idx < 512 * 25; idx += 256) {
    int d = idx / 25, l2 = idx % 25;
    outp[((size_t)b * 512 + d) * 25 + l2] = in[((size_t)b * 25 + l2) * 512 + d];
  }
}
__global__ void transpose_dl(const float* __restrict__ in, float* __restrict__ outp) {
  const int b = blockIdx.x, t = threadIdx.x;
  for (int idx = t; idx < 25 * 512; idx += 256) {
    int l2 = idx / 512, c = idx % 512;
    outp[((size_t)b * 25 + l2) * 512 + c] = in[((size_t)b * 512 + c) * 25 + l2];
  }
}

// ---------------- pipelined 32-layer LSTM (wave-autonomous) --------------
// Each wave owns 2 batches (lane half = batch); the h-recurrence stays
// inside the wave -> NO barriers in the step loop (LDS RAW within a wave
// is ordered by compiler lgkmcnt). 3 barriers per 8-step chunk.
// Cross-block: ring data + flags via RELAXED agent atomics (MALL), as R3/R4.
#define NLAY 32
#define NT   512
#define NB   128
#define NGRP 16
#define BGRP 8
#define CHT  8
#define NCHK 64
#define RT   64
#define RCHK (RT / CHT)

__device__ __forceinline__ int ld_rlx(int* p) {
  return __hip_atomic_load(p, __ATOMIC_RELAXED, __HIP_MEMORY_SCOPE_AGENT);
}
__device__ __forceinline__ void st_rlx(int* p, int v) {
  __hip_atomic_store(p, v, __ATOMIC_RELAXED, __HIP_MEMORY_SCOPE_AGENT);
}
__device__ __forceinline__ float ldf_rlx(const float* p) {
  return __hip_atomic_load(p, __ATOMIC_RELAXED, __HIP_MEMORY_SCOPE_AGENT);
}
__device__ __forceinline__ void stf_rlx(float* p, float v) {
  __hip_atomic_store(p, v, __ATOMIC_RELAXED, __HIP_MEMORY_SCOPE_AGENT);
}
__device__ __forceinline__ float tanh_fast(float x) {
  return 1.f - 2.f / (1.f + __expf(2.f * x));
}

__global__ __launch_bounds__(256) __attribute__((amdgpu_waves_per_eu(2, 2)))
void lstm_pipeline(const float* __restrict__ y0, float* __restrict__ yout,
                   float* __restrict__ ring, int* __restrict__ prod,
                   int* __restrict__ cons,
                   const float* __restrict__ Wih, const float* __restrict__ Whh,
                   const float* __restrict__ bih, const float* __restrict__ bhh) {
  const int l = blockIdx.x / NGRP;
  const int g = blockIdx.x % NGRP;
  const int t = threadIdx.x;
  const int wv   = t >> 6;             // wave 0..3
  const int lane = t & 63;
  const int half = lane >> 5;          // batch-in-wave 0..1
  const int u    = lane & 31;          // unit 0..24 active
  const int bi   = wv * 2 + half;      // batch-in-group 0..7
  const bool active = (u < 25);

  __shared__ _Float16 xbuf[CHT][BGRP][32];  // rows 64 B
  __shared__ _Float16 hbuf[BGRP][32];       // per-batch h (wave-private)

  // ---- weights packed half2: rows {u,25+u,50+u,75+u} ----
  h2v wih2[4][13], whh2[4][13];
  float bias_r[4];
  float c_reg = 0.f;
  {
    const int uc = active ? u : 24;
#pragma unroll
    for (int j = 0; j < 4; j++) {
      const float* wi = &Wih[((size_t)l * 100 + j * 25 + uc) * 25];
      const float* wh = &Whh[((size_t)l * 100 + j * 25 + uc) * 25];
#pragma unroll
      for (int k = 0; k < 13; k++) {
        float alo = wi[2 * k], ahi = (2 * k + 1 < 25) ? wi[2 * k + 1] : 0.f;
        float blo = wh[2 * k], bhi = (2 * k + 1 < 25) ? wh[2 * k + 1] : 0.f;
        wih2[j][k] = h2v{(_Float16)alo, (_Float16)ahi};
        whh2[j][k] = h2v{(_Float16)blo, (_Float16)bhi};
      }
      bias_r[j] = bih[l * 100 + j * 25 + uc] + bhh[l * 100 + j * 25 + uc];
    }
  }
  // zero xbuf pads + hbuf (pads must stay 0; never rewritten)
  for (int idx = t; idx < CHT * BGRP * 32; idx += 256) (&xbuf[0][0][0])[idx] = (_Float16)0.f;
  for (int idx = t; idx < BGRP * 32; idx += 256) (&hbuf[0][0])[idx] = (_Float16)0.f;
  __syncthreads();

  float* ring_out = ring + (((size_t)l * NB + g * BGRP + bi) * RT) * 25 + u;
  float* yout_out = yout + ((size_t)(g * BGRP + bi) * NT) * 25 + u;

  for (int n = 0; n < NCHK; n++) {
    if (t == 0) {
      if (l > 0) {
        int* p = &prod[(l - 1) * NGRP + g];
        while (ld_rlx(p) < n + 1) __builtin_amdgcn_s_sleep(1);
      }
      if (l < NLAY - 1 && n >= RCHK) {
        int* p = &cons[(l + 1) * NGRP + g];
        while (ld_rlx(p) < n - RCHK + 1) __builtin_amdgcn_s_sleep(1);
      }
    }
    __syncthreads();                                   // (A) poll done, xbuf free
    // stage chunk input (pow-2 index math; k>=25 lanes skip, pads stay 0)
    for (int idx = t; idx < CHT * BGRP * 32; idx += 256) {
      int k  = idx & 31;
      int b2 = (idx >> 5) & 7;
      int tc = idx >> 8;
      if (k < 25) {
        int tg = n * CHT + tc;
        int b  = g * BGRP + b2;
        float v;
        if (l == 0)
          v = y0[((size_t)b * NT + tg) * 25 + k];
        else
          v = ldf_rlx(&ring[(((size_t)(l - 1) * NB + b) * RT + (tg & (RT - 1))) * 25 + k]);
        xbuf[tc][b2][k] = (_Float16)v;
      }
    }
    __syncthreads();                                   // (B) staging visible
    if (t == 0 && l > 0) st_rlx(&cons[l * NGRP + g], n + 1);

    // ---- 8 steps, ZERO barriers (recurrence is wave-local) ----
#pragma unroll
    for (int tc = 0; tc < CHT; tc++) {
      const int tg = n * CHT + tc;
      if (active) {
        float a0 = bias_r[0], a1 = bias_r[1], a2 = bias_r[2], a3 = bias_r[3];
        const unsigned int* xr = (const unsigned int*)&xbuf[tc][bi][0];
        uint4 xa = *(const uint4*)(xr);
        uint4 xb = *(const uint4*)(xr + 4);
        uint4 xc = *(const uint4*)(xr + 8);
        unsigned int xd = xr[12];
        h2v xk[13] = {bch2(xa.x), bch2(xa.y), bch2(xa.z), bch2(xa.w),
                      bch2(xb.x), bch2(xb.y), bch2(xb.z), bch2(xb.w),
                      bch2(xc.x), bch2(xc.y), bch2(xc.z), bch2(xc.w),
                      bch2(xd)};
#pragma unroll
        for (int k = 0; k < 13; k++) {
          a0 = fdot2(wih2[0][k], xk[k], a0);
          a1 = fdot2(wih2[1][k], xk[k], a1);
          a2 = fdot2(wih2[2][k], xk[k], a2);
          a3 = fdot2(wih2[3][k], xk[k], a3);
        }
        const unsigned int* hr = (const unsigned int*)&hbuf[bi][0];
        uint4 ha = *(const uint4*)(hr);
        uint4 hb = *(const uint4*)(hr + 4);
        uint4 hc = *(const uint4*)(hr + 8);
        unsigned int hd = hr[12];
        h2v hk[13] = {bch2(ha.x), bch2(ha.y), bch2(ha.z), bch2(ha.w),
                      bch2(hb.x), bch2(hb.y), bch2(hb.z), bch2(hb.w),
                      bch2(hc.x), bch2(hc.y), bch2(hc.z), bch2(hc.w),
                      bch2(hd)};
#pragma unroll
        for (int k = 0; k < 13; k++) {
          a0 = fdot2(whh2[0][k], hk[k], a0);
          a1 = fdot2(whh2[1][k], hk[k], a1);
          a2 = fdot2(whh2[2][k], hk[k], a2);
          a3 = fdot2(whh2[3][k], hk[k], a3);
        }
        float si = 1.f / (1.f + __expf(-a0));
        float sf = 1.f / (1.f + __expf(-a1));
        float so = 1.f / (1.f + __expf(-a3));
        c_reg = sf * c_reg + si * tanh_fast(a2);
        float h = so * tanh_fast(c_reg);
        hbuf[bi][u] = (_Float16)h;                     // wave-local; no barrier
        if (l == NLAY - 1)
          yout_out[(size_t)tg * 25] = h;
        else
          stf_rlx(&ring_out[(size_t)(tg & (RT - 1)) * 25], h);
      }
    }
    asm volatile("s_waitcnt vmcnt(0)" ::: "memory");   // ring stores at MALL
    __syncthreads();                                   // (C) all waves done
    if (t == 0 && l < NLAY - 1) st_rlx(&prod[l * NGRP + g], n + 1);
  }
}

// =====================================================================
extern "C" void kernel_launch(void* const* d_in, const int* in_sizes, int n_in,
                              void* d_out, int out_size, void* d_ws, size_t ws_size,
                              hipStream_t stream) {
  const float* x     = (const float*)d_in[0];
  const float* cross = (const float*)d_in[1];
  const float* Wq_s = (const float*)d_in[2];  const float* bq_s = (const float*)d_in[3];
  const float* Wk_s = (const float*)d_in[4];  const float* bk_s = (const float*)d_in[5];
  const float* Wv_s = (const float*)d_in[6];  const float* bv_s = (const float*)d_in[7];
  const float* Wo_s = (const float*)d_in[8];  const float* bo_s = (const float*)d_in[9];
  const float* Wq_c = (const float*)d_in[10]; const float* bq_c = (const float*)d_in[11];
  const float* Wk_c = (const float*)d_in[12]; const float* bk_c = (const float*)d_in[13];
  const float* Wv_c = (const float*)d_in[14]; const float* bv_c = (const float*)d_in[15];
  const float* Wo_c = (const float*)d_in[16]; const float* bo_c = (const float*)d_in[17];
  const float* g1 = (const float*)d_in[18]; const float* b1 = (const float*)d_in[19];
  const float* g2 = (const float*)d_in[20]; const float* b2 = (const float*)d_in[21];
  const float* g3 = (const float*)d_in[22]; const float* b3 = (const float*)d_in[23];
  const float* Wih = (const float*)d_in[24];
  const float* Whh = (const float*)d_in[25];
  const float* bih = (const float*)d_in[26];
  const float* bhh = (const float*)d_in[27];
  const float* Wc  = (const float*)d_in[28]; const float* bc = (const float*)d_in[29];
  float* out = (float*)d_out;
  float* ws  = (float*)d_ws;

  // ---- workspace (floats); time-multiplexed regions (proven R4 map) -----
  constexpr size_t A  = 1638400;    // 3200*512
  constexpr size_t C6 = 6291456;    // 12288*512
  float* x1    = ws;
  float* Qc    = ws + A;
  // self phase
  float* Qs    = ws + 2 * A;
  float* Ks    = ws + 3 * A;
  float* Vs    = ws + 4 * A;
  float* attns = ws + 5 * A;
  float* tmp   = ws + 6 * A;
  float* Ps    = ws + 7 * A;
  // cross phase
  float* Kc    = ws + 2 * A;
  float* Vc    = ws + 2 * A + C6;
  float* attnc = ws + 2 * A + 2 * C6;
  float* Pc    = attnc + A;
  float* tmp2  = ws + 6 * A;
  float* x2    = ws + 3 * A;
  // lstm / post
  float* y0b   = ws + 4 * A;
  float* youtb = ws + 5 * A;
  float* ringb = ws + 6 * A;
  float* ytb   = ws + 2 * A;                     // after cross phase dead
  float* fy    = ws + 5 * A;                     // after youtb dead
  // f16 weight arena: 9 x 262144 halves
  _Float16* WTall = (_Float16*)(ws + 20000000);
  int* ctr = (int*)(ws + 21179648);

  dim3 blk(256);
  // ---- prep: all weight converts in ONE dispatch ----
  WPtrs wp;
  wp.p[0] = Wq_s; wp.p[1] = Wk_s; wp.p[2] = Wv_s; wp.p[3] = Wo_s;
  wp.p[4] = Wq_c; wp.p[5] = Wk_c; wp.p[6] = Wv_c; wp.p[7] = Wo_c;
  wp.p[8] = Wc;
  prep_weights<<<dim3(16, 16, 9), blk, 0, stream>>>(wp, WTall);
  hipMemsetAsync(ctr, 0, 1024 * sizeof(int), stream);
  _Float16* WT[9];
  for (int i = 0; i < 9; i++) WT[i] = WTall + (size_t)i * 262144;

  // ---- self attention ----
  gemm3<<<dim3(24, 50), blk, 0, stream>>>(x, WT[0], WT[1], WT[2],
                                          bq_s, bk_s, bv_s, Qs, Ks, Vs, 3200);
  attn_scores<25><<<dim3(8, 128), blk, 0, stream>>>(Qs, Ks, Ps);
  attn_out<25><<<dim3(8, 128), blk, 0, stream>>>(Ps, Vs, attns);
  gemm3<<<dim3(8, 50), blk, 0, stream>>>(attns, WT[3], WT[3], WT[3],
                                         bo_s, bo_s, bo_s, tmp, tmp, tmp, 3200);
  add_ln<<<3200, 128, 0, stream>>>(x, tmp, g1, b1, x1);
  // ---- cross attention ----
  gemm3<<<dim3(8, 50), blk, 0, stream>>>(x1, WT[4], WT[4], WT[4],
                                         bq_c, bq_c, bq_c, Qc, Qc, Qc, 3200);
  gemm3<<<dim3(16, 192), blk, 0, stream>>>(cross, WT[5], WT[6], WT[6],
                                           bk_c, bv_c, bv_c, Kc, Vc, Vc, 12288);
  attn_scores<96><<<dim3(8, 128), blk, 0, stream>>>(Qc, Kc, Pc);
  attn_out<96><<<dim3(8, 128), blk, 0, stream>>>(Pc, Vc, attnc);
  gemm3<<<dim3(8, 50), blk, 0, stream>>>(attnc, WT[7], WT[7], WT[7],
                                         bo_c, bo_c, bo_c, tmp2, tmp2, tmp2, 3200);
  add_ln<<<3200, 128, 0, stream>>>(x1, tmp2, g2, b2, x2);
  // ---- LSTM over feature axis ----
  transpose_ld<<<128, 256, 0, stream>>>(x2, y0b);
  lstm_pipeline<<<NLAY * NGRP, 256, 0, stream>>>(y0b, youtb, ringb, ctr, ctr + 512,
                                                 Wih, Whh, bih, bhh);
  // ---- pointwise conv over channels + final LN ----
  transpose_dl<<<128, 256, 0, stream>>>(youtb, ytb);
  gemm3<<<dim3(8, 50), blk, 0, stream>>>(ytb, WT[8], WT[8], WT[8],
                                         bc, bc, bc, fy, fy, fy, 3200);
  add_ln<<<3200, 128, 0, stream>>>(x2, fy, g3, b3, out);
}